// Round 1
// baseline (415.467 us; speedup 1.0000x reference)
//
#include <hip/hip_runtime.h>
#include <hip/hip_bf16.h>

// RelativeAttention: out = ((softmax(((QK^T)*s + Q.rel)*s with mask) V) Wo + bo
// B=4 S=1024 D=1024 H=16 dk=64.  All matmuls in bf16 MFMA (16x16x32), f32 accum.

typedef unsigned short u16;
typedef unsigned int u32;
typedef __attribute__((ext_vector_type(8))) short bf16x8;
typedef __attribute__((ext_vector_type(4))) float f32x4;

#define SB 1024
#define DM 1024
#define NHD 16
#define DKH 64
#define NBATCH 4

__device__ __forceinline__ u16 f2bf(float x) {
  union { __hip_bfloat16 b; u16 u; } c;
  c.b = __float2bfloat16(x);
  return c.u;
}

__device__ __forceinline__ f32x4 mfma16(bf16x8 a, bf16x8 b, f32x4 c) {
  return __builtin_amdgcn_mfma_f32_16x16x32_bf16(a, b, c, 0, 0, 0);
}

__device__ __forceinline__ bf16x8 cvt8(const float* __restrict__ p) {
  float4 v0 = *(const float4*)(p);
  float4 v1 = *(const float4*)(p + 4);
  bf16x8 r;
  r[0] = (short)f2bf(v0.x); r[1] = (short)f2bf(v0.y);
  r[2] = (short)f2bf(v0.z); r[3] = (short)f2bf(v0.w);
  r[4] = (short)f2bf(v1.x); r[5] = (short)f2bf(v1.y);
  r[6] = (short)f2bf(v1.z); r[7] = (short)f2bf(v1.w);
  return r;
}

// ---------------- f32 -> bf16 for the 3 input activations ----------------
__global__ void ra_convert_in(const float* __restrict__ q, const float* __restrict__ k,
                              const float* __restrict__ v,
                              u16* __restrict__ Xq, u16* __restrict__ Xk, u16* __restrict__ Xv)
{
  const int z = blockIdx.y;
  const float* src = (z == 0) ? q : (z == 1) ? k : v;
  u16* dst = (z == 0) ? Xq : (z == 1) ? Xk : Xv;
  const int n4 = NBATCH * SB * DM / 4;
  int idx = blockIdx.x * blockDim.x + threadIdx.x;
  int stride = gridDim.x * blockDim.x;
  for (int i = idx; i < n4; i += stride) {
    float4 v4 = *((const float4*)src + i);
    uint2 o;
    o.x = (u32)f2bf(v4.x) | ((u32)f2bf(v4.y) << 16);
    o.y = (u32)f2bf(v4.z) | ((u32)f2bf(v4.w) << 16);
    *((uint2*)dst + i) = o;
  }
}

// ---------------- W (f32 [k][n]) -> W^T (bf16 [n][k]) ----------------
__global__ void ra_transpose_w(const float* __restrict__ Wq, const float* __restrict__ Wk,
                               const float* __restrict__ Wv, const float* __restrict__ Wo,
                               u16* __restrict__ WqT, u16* __restrict__ WkT,
                               u16* __restrict__ WvT, u16* __restrict__ WoT)
{
  const int z = blockIdx.z;
  const float* W = (z == 0) ? Wq : (z == 1) ? Wk : (z == 2) ? Wv : Wo;
  u16* WT = (z == 0) ? WqT : (z == 1) ? WkT : (z == 2) ? WvT : WoT;
  __shared__ float tile[32][33];
  const int x0 = blockIdx.x * 32, y0 = blockIdx.y * 32;
  const int tx = threadIdx.x, ty = threadIdx.y;
#pragma unroll
  for (int yy = 0; yy < 4; ++yy) {
    int r = ty + yy * 8;
    tile[r][tx] = W[(size_t)(y0 + r) * DM + x0 + tx];
  }
  __syncthreads();
#pragma unroll
  for (int yy = 0; yy < 4; ++yy) {
    int r = ty + yy * 8;
    WT[(size_t)(x0 + r) * DM + y0 + tx] = f2bf(tile[tx][r]);
  }
}

// ---------------- shared 128x128x1024 bf16 GEMM core ----------------
// A: [M][1024] bf16 row-major, Bt: [N][1024] bf16 (= B^T). 256 threads, 4 waves,
// wave grid 2x2, each wave 4x4 frags of 16x16. LDS rows padded to 72 (2-way max).
__device__ __forceinline__ void gemm_core_128(const u16* __restrict__ A, const u16* __restrict__ Bt,
                                              int bm0, int bn0, u16* sh, f32x4 (&acc)[4][4])
{
  u16* As = sh;             // [128][72]
  u16* Bs = sh + 128 * 72;  // [128][72]
  const int tid = threadIdx.x;
  const int lane = tid & 63, wid = tid >> 6;
  const int l15 = lane & 15, l4 = lane >> 4;
  const int wr = (wid >> 1) * 64, wc = (wid & 1) * 64;
  for (int k0 = 0; k0 < DM; k0 += 64) {
#pragma unroll
    for (int it = 0; it < 4; ++it) {
      int c = tid + it * 256;
      int rw = c >> 3, kc = c & 7;
      *(uint4*)(As + rw * 72 + kc * 8) = *(const uint4*)(A + (size_t)(bm0 + rw) * DM + k0 + kc * 8);
      *(uint4*)(Bs + rw * 72 + kc * 8) = *(const uint4*)(Bt + (size_t)(bn0 + rw) * DM + k0 + kc * 8);
    }
    __syncthreads();
#pragma unroll
    for (int kf = 0; kf < 2; ++kf) {
      bf16x8 a[4], b[4];
#pragma unroll
      for (int mf = 0; mf < 4; ++mf)
        a[mf] = *(const bf16x8*)(As + (wr + mf * 16 + l15) * 72 + kf * 32 + l4 * 8);
#pragma unroll
      for (int nf = 0; nf < 4; ++nf)
        b[nf] = *(const bf16x8*)(Bs + (wc + nf * 16 + l15) * 72 + kf * 32 + l4 * 8);
#pragma unroll
      for (int mf = 0; mf < 4; ++mf)
#pragma unroll
        for (int nf = 0; nf < 4; ++nf)
          acc[mf][nf] = mfma16(a[mf], b[nf], acc[mf][nf]);
    }
    __syncthreads();
  }
}

// ---------------- projections: q/k -> [bh][s][dk], v -> [bh][dk][s] ----------------
__global__ __launch_bounds__(256, 2)
void ra_proj_gemm(const u16* __restrict__ Xq, const u16* __restrict__ Xk, const u16* __restrict__ Xv,
                  const u16* __restrict__ WqT, const u16* __restrict__ WkT, const u16* __restrict__ WvT,
                  const float* __restrict__ bq, const float* __restrict__ bk, const float* __restrict__ bv,
                  u16* __restrict__ q_ws, u16* __restrict__ k_ws, u16* __restrict__ vT_ws)
{
  __shared__ alignas(16) u16 sh[128 * 72 * 2];
  const int mode = blockIdx.z;
  const u16* A  = (mode == 0) ? Xq : (mode == 1) ? Xk : Xv;
  const u16* Bt = (mode == 0) ? WqT : (mode == 1) ? WkT : WvT;
  const float* bias = (mode == 0) ? bq : (mode == 1) ? bk : bv;
  const int bm0 = blockIdx.x * 128, bn0 = blockIdx.y * 128;
  f32x4 acc[4][4] = {};
  gemm_core_128(A, Bt, bm0, bn0, sh, acc);
  const int tid = threadIdx.x;
  const int lane = tid & 63, wid = tid >> 6;
  const int l15 = lane & 15, l4 = lane >> 4;
  const int wr = (wid >> 1) * 64, wc = (wid & 1) * 64;
  const int b_idx = bm0 >> 10;
  const int srow0 = bm0 & (SB - 1);
  if (mode < 2) {
    u16* outp = (mode == 0) ? q_ws : k_ws;
#pragma unroll
    for (int nf = 0; nf < 4; ++nf) {
      int nn = bn0 + wc + nf * 16 + l15;
      float bv_ = bias[nn];
      int h = nn >> 6, d = nn & 63;
#pragma unroll
      for (int mf = 0; mf < 4; ++mf)
#pragma unroll
        for (int r = 0; r < 4; ++r) {
          int m = wr + mf * 16 + l4 * 4 + r;
          outp[((size_t)(b_idx * NHD + h) * SB + srow0 + m) * DKH + d] = f2bf(acc[mf][nf][r] + bv_);
        }
    }
  } else {
    // transpose tile through LDS so vT writes are coalesced
    u16* ct = sh;  // [128][136]
#pragma unroll
    for (int nf = 0; nf < 4; ++nf) {
      int nl = wc + nf * 16 + l15;
      float bv_ = bias[bn0 + nl];
#pragma unroll
      for (int mf = 0; mf < 4; ++mf)
#pragma unroll
        for (int r = 0; r < 4; ++r) {
          int m = wr + mf * 16 + l4 * 4 + r;
          ct[nl * 136 + m] = f2bf(acc[mf][nf][r] + bv_);
        }
    }
    __syncthreads();
#pragma unroll
    for (int it = 0; it < 8; ++it) {
      int c = tid + it * 256;
      int n = c >> 4, mc2 = c & 15;
      uint4 v = *(const uint4*)(ct + n * 136 + mc2 * 8);
      int nn = bn0 + n;
      int h = nn >> 6, d = nn & 63;
      *(uint4*)(vT_ws + ((size_t)(b_idx * NHD + h) * DKH + d) * SB + srow0 + mc2 * 8) = v;
    }
  }
}

// ---------------- final projection: out = x @ Wo + bo (f32 out) ----------------
__global__ __launch_bounds__(256, 2)
void ra_out_gemm(const u16* __restrict__ X, const u16* __restrict__ WoT,
                 const float* __restrict__ bo, float* __restrict__ out)
{
  __shared__ alignas(16) u16 sh[128 * 72 * 2];
  const int bm0 = blockIdx.x * 128, bn0 = blockIdx.y * 128;
  f32x4 acc[4][4] = {};
  gemm_core_128(X, WoT, bm0, bn0, sh, acc);
  const int tid = threadIdx.x;
  const int lane = tid & 63, wid = tid >> 6;
  const int l15 = lane & 15, l4 = lane >> 4;
  const int wr = (wid >> 1) * 64, wc = (wid & 1) * 64;
#pragma unroll
  for (int nf = 0; nf < 4; ++nf) {
    int nn = bn0 + wc + nf * 16 + l15;
    float bv_ = bo[nn];
#pragma unroll
    for (int mf = 0; mf < 4; ++mf)
#pragma unroll
      for (int r = 0; r < 4; ++r) {
        int m = wr + mf * 16 + l4 * 4 + r;
        out[(size_t)(bm0 + m) * DM + nn] = acc[mf][nf][r] + bv_;
      }
  }
}

// ---------------- fused attention ----------------
// Block = (batch g, i-tile of 16 rows) covering ALL 16 heads of that batch, so the
// rel[i0..i0+16) slice (f32) is read exactly once per block. 8 waves / 512 threads.
// s1: per-bh MFMA M=i, N=j.  s2: per-i MFMA M=bh, N=j.  Combined in LDS f32 tile.
// Online softmax with 2 lanes per (bh,i) row. PV per-bh with V^T layout.
__global__ __launch_bounds__(512, 2)
void ra_attn(const u16* __restrict__ q_ws, const u16* __restrict__ k_ws,
             const u16* __restrict__ vT_ws, const int* __restrict__ mask,
             const float* __restrict__ rel, u16* __restrict__ x_ws)
{
  __shared__ alignas(16) char smem[93440];
  u16*   q_lds    = (u16*)smem;               // addr: bh*1160 + i*72 + d   (padded both ways)
  float* s_tile   = (float*)(smem + 37120);   // addr: (bh*16+i)*33 + j     [16][16][33] f32
  u16*   p_tile   = (u16*)(smem + 70912);     // addr: (bh*16+i)*40 + j     [16][16][40] bf16
  float* f_tile   = (float*)(smem + 91392);   // [256] rescale factors
  float* sum_tile = (float*)(smem + 92416);   // [256] softmax denominators

  const int tid = threadIdx.x;
  const int wid = tid >> 6, lane = tid & 63;
  const int l15 = lane & 15, l4 = lane >> 4;
  const int g = blockIdx.x;        // batch (= bh group of 16 heads)
  const int i0 = blockIdx.y * 16;  // query-row tile
  const int bh0 = g * NHD;

  // stage q tile: [16 bh][16 i][64 d]
#pragma unroll
  for (int it = 0; it < 4; ++it) {
    int c = tid + it * 512;
    int bh = c >> 7, ii = (c >> 3) & 15, dc = c & 7;
    uint4 v = *(const uint4*)(q_ws + ((size_t)(bh0 + bh) * SB + i0 + ii) * DKH + dc * 8);
    *(uint4*)(q_lds + bh * 1160 + ii * 72 + dc * 8) = v;
  }
  __syncthreads();

  f32x4 acc_o[2][4] = {};
  float m_run = -1e30f, l_run = 0.f;
  const int row = tid >> 1;      // softmax row = bh*16+i, two lanes per row
  const int s_i = row & 15;
  const int jh = tid & 1;
  const float scl1 = 0.125f, scl2 = 0.015625f;  // 1/sqrt(dk), 1/dk

  for (int jt = 0; jt < 32; ++jt) {
    const int jbase = jt * 32;
    // ---- Phase A1: s1 = (q.k^T) * scale^2, each wave owns 2 bh ----
#pragma unroll
    for (int bx = 0; bx < 2; ++bx) {
      const int bh = wid * 2 + bx;
      const u16* qp = q_lds + bh * 1160 + l15 * 72 + l4 * 8;
      bf16x8 a0 = *(const bf16x8*)qp;
      bf16x8 a1 = *(const bf16x8*)(qp + 32);
      f32x4 acc1[2] = {};
#pragma unroll
      for (int nf = 0; nf < 2; ++nf) {
        const u16* kp = k_ws + ((size_t)(bh0 + bh) * SB + jbase + nf * 16 + l15) * DKH + l4 * 8;
        bf16x8 b0 = *(const bf16x8*)kp;
        bf16x8 b1 = *(const bf16x8*)(kp + 32);
        acc1[nf] = mfma16(a0, b0, acc1[nf]);
        acc1[nf] = mfma16(a1, b1, acc1[nf]);
      }
#pragma unroll
      for (int nf = 0; nf < 2; ++nf)
#pragma unroll
        for (int r = 0; r < 4; ++r)
          s_tile[(bh * 16 + l4 * 4 + r) * 33 + nf * 16 + l15] = acc1[nf][r] * scl2;
    }
    __syncthreads();
    // ---- Phase A2: += (q.rel[i]) * scale, each wave owns 2 i ----
#pragma unroll
    for (int ix = 0; ix < 2; ++ix) {
      const int i2 = wid * 2 + ix;
      const u16* qp = q_lds + l15 * 1160 + i2 * 72 + l4 * 8;  // M dim = bh
      bf16x8 a0 = *(const bf16x8*)qp;
      bf16x8 a1 = *(const bf16x8*)(qp + 32);
      f32x4 acc2[2] = {};
#pragma unroll
      for (int nf = 0; nf < 2; ++nf) {
        const float* rp = rel + ((size_t)(i0 + i2) * SB + jbase + nf * 16 + l15) * DKH + l4 * 8;
        bf16x8 b0 = cvt8(rp);
        bf16x8 b1 = cvt8(rp + 32);
        acc2[nf] = mfma16(a0, b0, acc2[nf]);
        acc2[nf] = mfma16(a1, b1, acc2[nf]);
      }
#pragma unroll
      for (int nf = 0; nf < 2; ++nf)
#pragma unroll
        for (int r = 0; r < 4; ++r)
          s_tile[((l4 * 4 + r) * 16 + i2) * 33 + nf * 16 + l15] += acc2[nf][r] * scl1;
    }
    __syncthreads();
    // ---- Phase B: masked online softmax (row-wise, 2 lanes/row) ----
    {
      const float* srow = s_tile + row * 33 + jh * 16;
      const int4* m4 = (const int4*)(mask + ((size_t)g * SB + i0 + s_i) * SB + jbase + jh * 16);
      int mv[16];
#pragma unroll
      for (int q4 = 0; q4 < 4; ++q4) {
        int4 mm = m4[q4];
        mv[q4 * 4 + 0] = mm.x; mv[q4 * 4 + 1] = mm.y;
        mv[q4 * 4 + 2] = mm.z; mv[q4 * 4 + 3] = mm.w;
      }
      float sv[16];
      float tmax = -3e38f;
#pragma unroll
      for (int jj = 0; jj < 16; ++jj) {
        float v = srow[jj];
        v = (mv[jj] == 0) ? -1e9f : v;
        sv[jj] = v;
        tmax = fmaxf(tmax, v);
      }
      tmax = fmaxf(tmax, __shfl_xor(tmax, 1));
      const float m_new = fmaxf(m_run, tmax);
      const float fsc = __expf(m_run - m_new);
      float psum = 0.f;
      u32 up[8];
#pragma unroll
      for (int jj = 0; jj < 8; ++jj) {
        float p0 = __expf(sv[2 * jj] - m_new);
        float p1 = __expf(sv[2 * jj + 1] - m_new);
        psum += p0 + p1;
        up[jj] = (u32)f2bf(p0) | ((u32)f2bf(p1) << 16);
      }
      psum += __shfl_xor(psum, 1);
      l_run = l_run * fsc + psum;
      m_run = m_new;
      f_tile[row] = fsc;
      uint4* pd = (uint4*)(p_tile + row * 40 + jh * 16);
      uint4 w0; w0.x = up[0]; w0.y = up[1]; w0.z = up[2]; w0.w = up[3];
      uint4 w1; w1.x = up[4]; w1.y = up[5]; w1.z = up[6]; w1.w = up[7];
      pd[0] = w0; pd[1] = w1;
    }
    __syncthreads();
    // ---- Phase C: O = O*f + P.V (wave-local p/f rows; no barrier needed after) ----
#pragma unroll
    for (int bx = 0; bx < 2; ++bx) {
      const int bh = wid * 2 + bx;
      float4 f4 = *(const float4*)(f_tile + bh * 16 + l4 * 4);
      bf16x8 pa = *(const bf16x8*)(p_tile + (bh * 16 + l15) * 40 + l4 * 8);
#pragma unroll
      for (int df = 0; df < 4; ++df) {
        f32x4 c = acc_o[bx][df];
        c[0] *= f4.x; c[1] *= f4.y; c[2] *= f4.z; c[3] *= f4.w;
        const u16* vp = vT_ws + ((size_t)(bh0 + bh) * DKH + df * 16 + l15) * SB + jbase + l4 * 8;
        bf16x8 vb = *(const bf16x8*)vp;
        acc_o[bx][df] = mfma16(pa, vb, c);
      }
    }
  }
  // ---- epilogue: divide by softmax sum, write x[b][s][h*64+d] bf16 ----
  sum_tile[row] = l_run;
  __syncthreads();
#pragma unroll
  for (int bx = 0; bx < 2; ++bx) {
    const int bh = wid * 2 + bx;
    float4 s4 = *(const float4*)(sum_tile + bh * 16 + l4 * 4);
    float inv[4] = {1.f / s4.x, 1.f / s4.y, 1.f / s4.z, 1.f / s4.w};
#pragma unroll
    for (int df = 0; df < 4; ++df)
#pragma unroll
      for (int r = 0; r < 4; ++r) {
        const int i = l4 * 4 + r;
        float val = acc_o[bx][df][r] * inv[r];
        x_ws[((size_t)g * SB + i0 + i) * DM + bh * DKH + df * 16 + l15] = f2bf(val);
      }
  }
}

// ---------------- launch ----------------
extern "C" void kernel_launch(void* const* d_in, const int* in_sizes, int n_in,
                              void* d_out, int out_size, void* d_ws, size_t ws_size,
                              hipStream_t stream) {
  const float* query = (const float*)d_in[0];
  const float* key_  = (const float*)d_in[1];
  const float* value = (const float*)d_in[2];
  const int*   mask  = (const int*)d_in[3];
  const float* rel   = (const float*)d_in[4];
  const float* Wq = (const float*)d_in[5];
  const float* Wk = (const float*)d_in[6];
  const float* Wv = (const float*)d_in[7];
  const float* Wo = (const float*)d_in[8];
  const float* bq = (const float*)d_in[9];
  const float* bk = (const float*)d_in[10];
  const float* bv = (const float*)d_in[11];
  const float* bo = (const float*)d_in[12];
  float* out = (float*)d_out;
  char* ws = (char*)d_ws;

  // workspace layout (64 MB total)
  u16* Xq   = (u16*)(ws + (0ull));
  u16* Xk   = (u16*)(ws + (8ull << 20));
  u16* Xv   = (u16*)(ws + (16ull << 20));
  u16* WqT  = (u16*)(ws + (24ull << 20));
  u16* WkT  = (u16*)(ws + (26ull << 20));
  u16* WvT  = (u16*)(ws + (28ull << 20));
  u16* WoT  = (u16*)(ws + (30ull << 20));
  u16* q_ws = (u16*)(ws + (32ull << 20));
  u16* k_ws = (u16*)(ws + (40ull << 20));
  u16* vT_ws= (u16*)(ws + (48ull << 20));
  u16* x_ws = (u16*)(ws + (56ull << 20));

  ra_convert_in<<<dim3(1024, 3), 256, 0, stream>>>(query, key_, value, Xq, Xk, Xv);
  ra_transpose_w<<<dim3(32, 32, 4), dim3(32, 8), 0, stream>>>(Wq, Wk, Wv, Wo, WqT, WkT, WvT, WoT);
  ra_proj_gemm<<<dim3(32, 8, 3), 256, 0, stream>>>(Xq, Xk, Xv, WqT, WkT, WvT, bq, bk, bv,
                                                   q_ws, k_ws, vT_ws);
  ra_attn<<<dim3(4, 64), 512, 0, stream>>>(q_ws, k_ws, vT_ws, mask, rel, x_ws);
  ra_out_gemm<<<dim3(32, 8), 256, 0, stream>>>(x_ws, WoT, bo, out);
}

// Round 2
// 363.573 us; speedup vs baseline: 1.1427x; 1.1427x over previous
//
#include <hip/hip_runtime.h>
#include <hip/hip_bf16.h>

// RelativeAttention: out = ((softmax(((QK^T)*s + Q.rel)*s with mask) V) Wo + bo
// B=4 S=1024 D=1024 H=16 dk=64.  All matmuls in bf16 MFMA (16x16x32), f32 accum.

typedef unsigned short u16;
typedef unsigned int u32;
typedef __attribute__((ext_vector_type(8))) short bf16x8;
typedef __attribute__((ext_vector_type(4))) float f32x4;

#define SB 1024
#define DM 1024
#define NHD 16
#define DKH 64
#define NBATCH 4

__device__ __forceinline__ u16 f2bf(float x) {
  union { __hip_bfloat16 b; u16 u; } c;
  c.b = __float2bfloat16(x);
  return c.u;
}

__device__ __forceinline__ f32x4 mfma16(bf16x8 a, bf16x8 b, f32x4 c) {
  return __builtin_amdgcn_mfma_f32_16x16x32_bf16(a, b, c, 0, 0, 0);
}

__device__ __forceinline__ bf16x8 cvt8r(float4 v0, float4 v1) {
  bf16x8 r;
  r[0] = (short)f2bf(v0.x); r[1] = (short)f2bf(v0.y);
  r[2] = (short)f2bf(v0.z); r[3] = (short)f2bf(v0.w);
  r[4] = (short)f2bf(v1.x); r[5] = (short)f2bf(v1.y);
  r[6] = (short)f2bf(v1.z); r[7] = (short)f2bf(v1.w);
  return r;
}

// ---------------- f32 -> bf16 for the 3 input activations ----------------
__global__ void ra_convert_in(const float* __restrict__ q, const float* __restrict__ k,
                              const float* __restrict__ v,
                              u16* __restrict__ Xq, u16* __restrict__ Xk, u16* __restrict__ Xv)
{
  const int z = blockIdx.y;
  const float* src = (z == 0) ? q : (z == 1) ? k : v;
  u16* dst = (z == 0) ? Xq : (z == 1) ? Xk : Xv;
  const int n4 = NBATCH * SB * DM / 4;
  int idx = blockIdx.x * blockDim.x + threadIdx.x;
  int stride = gridDim.x * blockDim.x;
  for (int i = idx; i < n4; i += stride) {
    float4 v4 = *((const float4*)src + i);
    uint2 o;
    o.x = (u32)f2bf(v4.x) | ((u32)f2bf(v4.y) << 16);
    o.y = (u32)f2bf(v4.z) | ((u32)f2bf(v4.w) << 16);
    *((uint2*)dst + i) = o;
  }
}

// ---------------- W (f32 [k][n]) -> W^T (bf16 [n][k]) ----------------
__global__ void ra_transpose_w(const float* __restrict__ Wq, const float* __restrict__ Wk,
                               const float* __restrict__ Wv, const float* __restrict__ Wo,
                               u16* __restrict__ WqT, u16* __restrict__ WkT,
                               u16* __restrict__ WvT, u16* __restrict__ WoT)
{
  const int z = blockIdx.z;
  const float* W = (z == 0) ? Wq : (z == 1) ? Wk : (z == 2) ? Wv : Wo;
  u16* WT = (z == 0) ? WqT : (z == 1) ? WkT : (z == 2) ? WvT : WoT;
  __shared__ float tile[32][33];
  const int x0 = blockIdx.x * 32, y0 = blockIdx.y * 32;
  const int tx = threadIdx.x, ty = threadIdx.y;
#pragma unroll
  for (int yy = 0; yy < 4; ++yy) {
    int r = ty + yy * 8;
    tile[r][tx] = W[(size_t)(y0 + r) * DM + x0 + tx];
  }
  __syncthreads();
#pragma unroll
  for (int yy = 0; yy < 4; ++yy) {
    int r = ty + yy * 8;
    WT[(size_t)(x0 + r) * DM + y0 + tx] = f2bf(tile[tx][r]);
  }
}

// ---------------- shared 128x128x1024 bf16 GEMM core ----------------
__device__ __forceinline__ void gemm_core_128(const u16* __restrict__ A, const u16* __restrict__ Bt,
                                              int bm0, int bn0, u16* sh, f32x4 (&acc)[4][4])
{
  u16* As = sh;             // [128][72]
  u16* Bs = sh + 128 * 72;  // [128][72]
  const int tid = threadIdx.x;
  const int lane = tid & 63, wid = tid >> 6;
  const int l15 = lane & 15, l4 = lane >> 4;
  const int wr = (wid >> 1) * 64, wc = (wid & 1) * 64;
  for (int k0 = 0; k0 < DM; k0 += 64) {
#pragma unroll
    for (int it = 0; it < 4; ++it) {
      int c = tid + it * 256;
      int rw = c >> 3, kc = c & 7;
      *(uint4*)(As + rw * 72 + kc * 8) = *(const uint4*)(A + (size_t)(bm0 + rw) * DM + k0 + kc * 8);
      *(uint4*)(Bs + rw * 72 + kc * 8) = *(const uint4*)(Bt + (size_t)(bn0 + rw) * DM + k0 + kc * 8);
    }
    __syncthreads();
#pragma unroll
    for (int kf = 0; kf < 2; ++kf) {
      bf16x8 a[4], b[4];
#pragma unroll
      for (int mf = 0; mf < 4; ++mf)
        a[mf] = *(const bf16x8*)(As + (wr + mf * 16 + l15) * 72 + kf * 32 + l4 * 8);
#pragma unroll
      for (int nf = 0; nf < 4; ++nf)
        b[nf] = *(const bf16x8*)(Bs + (wc + nf * 16 + l15) * 72 + kf * 32 + l4 * 8);
#pragma unroll
      for (int mf = 0; mf < 4; ++mf)
#pragma unroll
        for (int nf = 0; nf < 4; ++nf)
          acc[mf][nf] = mfma16(a[mf], b[nf], acc[mf][nf]);
    }
    __syncthreads();
  }
}

// ---------------- projections: q/k -> [bh][s][dk], v -> [bh][dk][s] ----------------
__global__ __launch_bounds__(256, 2)
void ra_proj_gemm(const u16* __restrict__ Xq, const u16* __restrict__ Xk, const u16* __restrict__ Xv,
                  const u16* __restrict__ WqT, const u16* __restrict__ WkT, const u16* __restrict__ WvT,
                  const float* __restrict__ bq, const float* __restrict__ bk, const float* __restrict__ bv,
                  u16* __restrict__ q_ws, u16* __restrict__ k_ws, u16* __restrict__ vT_ws)
{
  __shared__ alignas(16) u16 sh[128 * 72 * 2];
  const int mode = blockIdx.z;
  const u16* A  = (mode == 0) ? Xq : (mode == 1) ? Xk : Xv;
  const u16* Bt = (mode == 0) ? WqT : (mode == 1) ? WkT : WvT;
  const float* bias = (mode == 0) ? bq : (mode == 1) ? bk : bv;
  const int bm0 = blockIdx.x * 128, bn0 = blockIdx.y * 128;
  f32x4 acc[4][4] = {};
  gemm_core_128(A, Bt, bm0, bn0, sh, acc);
  const int tid = threadIdx.x;
  const int lane = tid & 63, wid = tid >> 6;
  const int l15 = lane & 15, l4 = lane >> 4;
  const int wr = (wid >> 1) * 64, wc = (wid & 1) * 64;
  const int b_idx = bm0 >> 10;
  const int srow0 = bm0 & (SB - 1);
  if (mode < 2) {
    u16* outp = (mode == 0) ? q_ws : k_ws;
#pragma unroll
    for (int nf = 0; nf < 4; ++nf) {
      int nn = bn0 + wc + nf * 16 + l15;
      float bv_ = bias[nn];
      int h = nn >> 6, d = nn & 63;
#pragma unroll
      for (int mf = 0; mf < 4; ++mf)
#pragma unroll
        for (int r = 0; r < 4; ++r) {
          int m = wr + mf * 16 + l4 * 4 + r;
          outp[((size_t)(b_idx * NHD + h) * SB + srow0 + m) * DKH + d] = f2bf(acc[mf][nf][r] + bv_);
        }
    }
  } else {
    u16* ct = sh;  // [128][136]
#pragma unroll
    for (int nf = 0; nf < 4; ++nf) {
      int nl = wc + nf * 16 + l15;
      float bv_ = bias[bn0 + nl];
#pragma unroll
      for (int mf = 0; mf < 4; ++mf)
#pragma unroll
        for (int r = 0; r < 4; ++r) {
          int m = wr + mf * 16 + l4 * 4 + r;
          ct[nl * 136 + m] = f2bf(acc[mf][nf][r] + bv_);
        }
    }
    __syncthreads();
#pragma unroll
    for (int it = 0; it < 8; ++it) {
      int c = tid + it * 256;
      int n = c >> 4, mc2 = c & 15;
      uint4 v = *(const uint4*)(ct + n * 136 + mc2 * 8);
      int nn = bn0 + n;
      int h = nn >> 6, d = nn & 63;
      *(uint4*)(vT_ws + ((size_t)(b_idx * NHD + h) * DKH + d) * SB + srow0 + mc2 * 8) = v;
    }
  }
}

// ---------------- final projection: out = x @ Wo + bo (f32 out) ----------------
__global__ __launch_bounds__(256, 2)
void ra_out_gemm(const u16* __restrict__ X, const u16* __restrict__ WoT,
                 const float* __restrict__ bo, float* __restrict__ out)
{
  __shared__ alignas(16) u16 sh[128 * 72 * 2];
  const int bm0 = blockIdx.x * 128, bn0 = blockIdx.y * 128;
  f32x4 acc[4][4] = {};
  gemm_core_128(X, WoT, bm0, bn0, sh, acc);
  const int tid = threadIdx.x;
  const int lane = tid & 63, wid = tid >> 6;
  const int l15 = lane & 15, l4 = lane >> 4;
  const int wr = (wid >> 1) * 64, wc = (wid & 1) * 64;
#pragma unroll
  for (int nf = 0; nf < 4; ++nf) {
    int nn = bn0 + wc + nf * 16 + l15;
    float bv_ = bo[nn];
#pragma unroll
    for (int mf = 0; mf < 4; ++mf)
#pragma unroll
      for (int r = 0; r < 4; ++r) {
        int m = wr + mf * 16 + l4 * 4 + r;
        out[(size_t)(bm0 + m) * DM + nn] = acc[mf][nf][r] + bv_;
      }
  }
}

// ---------------- fused attention (register-prefetched, 2 barriers/iter) ----------------
// Block = (i-tile of 16, batch g) covering ALL 16 heads of that batch. 8 waves.
// Grid (64,4): sibling blocks sharing a rel i-slice have linear IDs == mod 8 -> same XCD L2.
// Per j-tile (32 cols):
//   A: s1 = q.K^T (K from regs) -> s1_tile (wave-local rows); reissue K(jt+1);
//      s2 = q.rel (rel from f32 regs) -> s2_tile; reissue rel(jt+1); mask+V(jt) issued at top.
//   bar | B: softmax over s1+s2 with mask regs -> p_tile, f_tile | bar
//   C: O = O*f + P.V (V in regs, P/f wave-local)
__global__ __launch_bounds__(512, 2)
void ra_attn(const u16* __restrict__ q_ws, const u16* __restrict__ k_ws,
             const u16* __restrict__ vT_ws, const int* __restrict__ mask,
             const float* __restrict__ rel, u16* __restrict__ x_ws)
{
  __shared__ alignas(16) char smem[133376];
  u16*   q_lds    = (u16*)smem;               // bh*1160 + i*72 + d
  float* s1_tile  = (float*)(smem + 37120);   // [(bh*16+i)][36]
  float* s2_tile  = (float*)(smem + 73984);   // [(bh*16+i)][36]
  u16*   p_tile   = (u16*)(smem + 110848);    // [(bh*16+i)][40]
  float* f_tile   = (float*)(smem + 131328);  // [256]
  float* sum_tile = (float*)(smem + 132352);  // [256]

  const int tid = threadIdx.x;
  const int wid = tid >> 6, lane = tid & 63;
  const int l15 = lane & 15, l4 = lane >> 4;
  const int g = blockIdx.y;        // batch
  const int i0 = blockIdx.x * 16;  // query-row tile
  const int bh0 = g * NHD;

  // stage q tile: [16 bh][16 i][64 d]
#pragma unroll
  for (int it = 0; it < 4; ++it) {
    int c = tid + it * 512;
    int bh = c >> 7, ii = (c >> 3) & 15, dc = c & 7;
    uint4 v = *(const uint4*)(q_ws + ((size_t)(bh0 + bh) * SB + i0 + ii) * DKH + dc * 8);
    *(uint4*)(q_lds + bh * 1160 + ii * 72 + dc * 8) = v;
  }
  __syncthreads();

  f32x4 acc_o[2][4] = {};
  float m_run = -1e30f, l_run = 0.f;
  const int row = tid >> 1;      // softmax row = bh*16+i
  const int s_i = row & 15;
  const int jh = tid & 1;
  const float scl1 = 0.125f, scl2 = 0.015625f;  // 1/sqrt(dk), 1/dk

  // loop-carried prefetch registers (single-buffered: reissued right after consumption)
  bf16x8 kr[2][2][2];     // [bx][nf][khalf]
  float4 rr_[2][2][4];    // [ix][nf][4]  (f32 rel, converted at use)

  // prologue: K(0), rel(0)
#pragma unroll
  for (int bx = 0; bx < 2; ++bx) {
    const int bh = wid * 2 + bx;
#pragma unroll
    for (int nf = 0; nf < 2; ++nf) {
      const u16* kp = k_ws + ((size_t)(bh0 + bh) * SB + nf * 16 + l15) * DKH + l4 * 8;
      kr[bx][nf][0] = *(const bf16x8*)kp;
      kr[bx][nf][1] = *(const bf16x8*)(kp + 32);
    }
  }
#pragma unroll
  for (int ix = 0; ix < 2; ++ix) {
    const int i2 = wid * 2 + ix;
#pragma unroll
    for (int nf = 0; nf < 2; ++nf) {
      const float* rp = rel + ((size_t)(i0 + i2) * SB + nf * 16 + l15) * DKH + l4 * 8;
      rr_[ix][nf][0] = *(const float4*)rp;
      rr_[ix][nf][1] = *(const float4*)(rp + 4);
      rr_[ix][nf][2] = *(const float4*)(rp + 32);
      rr_[ix][nf][3] = *(const float4*)(rp + 36);
    }
  }

  for (int jt = 0; jt < 32; ++jt) {
    const int jb = jt * 32;
    const int jbn = (jt < 31) ? jb + 32 : 0;  // clamped next-tile base (last-iter loads unused)

    // ---- issue mask(jt) + V(jt) first (oldest in vmcnt queue) ----
    int4 mr[4];
    {
      const int4* m4p = (const int4*)(mask + ((size_t)g * SB + i0 + s_i) * SB + jb + jh * 16);
      mr[0] = m4p[0]; mr[1] = m4p[1]; mr[2] = m4p[2]; mr[3] = m4p[3];
    }
    bf16x8 vr[2][4];
#pragma unroll
    for (int bx = 0; bx < 2; ++bx) {
      const int bh = wid * 2 + bx;
#pragma unroll
      for (int df = 0; df < 4; ++df) {
        const u16* vp = vT_ws + ((size_t)(bh0 + bh) * DKH + df * 16 + l15) * SB + jb + l4 * 8;
        vr[bx][df] = *(const bf16x8*)vp;
      }
    }

    // ---- Phase A-s1: q.K^T from kr -> s1_tile (wave-local rows) ----
#pragma unroll
    for (int bx = 0; bx < 2; ++bx) {
      const int bh = wid * 2 + bx;
      const u16* qp = q_lds + bh * 1160 + l15 * 72 + l4 * 8;
      bf16x8 a0 = *(const bf16x8*)qp;
      bf16x8 a1 = *(const bf16x8*)(qp + 32);
      f32x4 acc1[2] = {};
#pragma unroll
      for (int nf = 0; nf < 2; ++nf) {
        acc1[nf] = mfma16(a0, kr[bx][nf][0], acc1[nf]);
        acc1[nf] = mfma16(a1, kr[bx][nf][1], acc1[nf]);
      }
#pragma unroll
      for (int nf = 0; nf < 2; ++nf)
#pragma unroll
        for (int r = 0; r < 4; ++r)
          s1_tile[(bh * 16 + l4 * 4 + r) * 36 + nf * 16 + l15] = acc1[nf][r] * scl2;
    }
    // reissue K for jt+1 (same regs; last use was above)
#pragma unroll
    for (int bx = 0; bx < 2; ++bx) {
      const int bh = wid * 2 + bx;
#pragma unroll
      for (int nf = 0; nf < 2; ++nf) {
        const u16* kp = k_ws + ((size_t)(bh0 + bh) * SB + jbn + nf * 16 + l15) * DKH + l4 * 8;
        kr[bx][nf][0] = *(const bf16x8*)kp;
        kr[bx][nf][1] = *(const bf16x8*)(kp + 32);
      }
    }

    // ---- Phase A-s2: q.rel from rr_ -> s2_tile (cross-wave rows) ----
#pragma unroll
    for (int ix = 0; ix < 2; ++ix) {
      const int i2 = wid * 2 + ix;
      const u16* qp = q_lds + l15 * 1160 + i2 * 72 + l4 * 8;  // M dim = bh
      bf16x8 a0 = *(const bf16x8*)qp;
      bf16x8 a1 = *(const bf16x8*)(qp + 32);
      f32x4 acc2[2] = {};
#pragma unroll
      for (int nf = 0; nf < 2; ++nf) {
        bf16x8 b0 = cvt8r(rr_[ix][nf][0], rr_[ix][nf][1]);
        bf16x8 b1 = cvt8r(rr_[ix][nf][2], rr_[ix][nf][3]);
        acc2[nf] = mfma16(a0, b0, acc2[nf]);
        acc2[nf] = mfma16(a1, b1, acc2[nf]);
      }
#pragma unroll
      for (int nf = 0; nf < 2; ++nf)
#pragma unroll
        for (int r = 0; r < 4; ++r)
          s2_tile[((l4 * 4 + r) * 16 + i2) * 36 + nf * 16 + l15] = acc2[nf][r] * scl1;
    }
    // reissue rel for jt+1
#pragma unroll
    for (int ix = 0; ix < 2; ++ix) {
      const int i2 = wid * 2 + ix;
#pragma unroll
      for (int nf = 0; nf < 2; ++nf) {
        const float* rp = rel + ((size_t)(i0 + i2) * SB + jbn + nf * 16 + l15) * DKH + l4 * 8;
        rr_[ix][nf][0] = *(const float4*)rp;
        rr_[ix][nf][1] = *(const float4*)(rp + 4);
        rr_[ix][nf][2] = *(const float4*)(rp + 32);
        rr_[ix][nf][3] = *(const float4*)(rp + 36);
      }
    }
    __syncthreads();  // bar1: s2 visible to all waves

    // ---- Phase B: masked online softmax ----
    {
      const float* s1r = s1_tile + row * 36 + jh * 16;
      const float* s2r = s2_tile + row * 36 + jh * 16;
      float sv[16];
      float tmax = -3e38f;
#pragma unroll
      for (int q4 = 0; q4 < 4; ++q4) {
        float4 a = *(const float4*)(s1r + q4 * 4);
        float4 b = *(const float4*)(s2r + q4 * 4);
        int4 mm = mr[q4];
        float v0 = (mm.x == 0) ? -1e9f : a.x + b.x;
        float v1 = (mm.y == 0) ? -1e9f : a.y + b.y;
        float v2 = (mm.z == 0) ? -1e9f : a.z + b.z;
        float v3 = (mm.w == 0) ? -1e9f : a.w + b.w;
        sv[q4 * 4 + 0] = v0; sv[q4 * 4 + 1] = v1;
        sv[q4 * 4 + 2] = v2; sv[q4 * 4 + 3] = v3;
        tmax = fmaxf(tmax, fmaxf(fmaxf(v0, v1), fmaxf(v2, v3)));
      }
      tmax = fmaxf(tmax, __shfl_xor(tmax, 1));
      const float m_new = fmaxf(m_run, tmax);
      const float fsc = __expf(m_run - m_new);
      float psum = 0.f;
      u32 up[8];
#pragma unroll
      for (int jj = 0; jj < 8; ++jj) {
        float p0 = __expf(sv[2 * jj] - m_new);
        float p1 = __expf(sv[2 * jj + 1] - m_new);
        psum += p0 + p1;
        up[jj] = (u32)f2bf(p0) | ((u32)f2bf(p1) << 16);
      }
      psum += __shfl_xor(psum, 1);
      l_run = l_run * fsc + psum;
      m_run = m_new;
      f_tile[row] = fsc;
      uint4* pd = (uint4*)(p_tile + row * 40 + jh * 16);
      uint4 w0; w0.x = up[0]; w0.y = up[1]; w0.z = up[2]; w0.w = up[3];
      uint4 w1; w1.x = up[4]; w1.y = up[5]; w1.z = up[6]; w1.w = up[7];
      pd[0] = w0; pd[1] = w1;
    }
    __syncthreads();  // bar2: protects s-tiles from next iter's A overwrite

    // ---- Phase C: O = O*f + P.V (wave-local P/f, V in regs) ----
#pragma unroll
    for (int bx = 0; bx < 2; ++bx) {
      const int bh = wid * 2 + bx;
      float4 f4 = *(const float4*)(f_tile + bh * 16 + l4 * 4);
      bf16x8 pa = *(const bf16x8*)(p_tile + (bh * 16 + l15) * 40 + l4 * 8);
#pragma unroll
      for (int df = 0; df < 4; ++df) {
        f32x4 c = acc_o[bx][df];
        c[0] *= f4.x; c[1] *= f4.y; c[2] *= f4.z; c[3] *= f4.w;
        acc_o[bx][df] = mfma16(pa, vr[bx][df], c);
      }
    }
  }
  // ---- epilogue: divide by softmax sum, write x[b][s][h*64+d] bf16 ----
  sum_tile[row] = l_run;
  __syncthreads();
#pragma unroll
  for (int bx = 0; bx < 2; ++bx) {
    const int bh = wid * 2 + bx;
    float4 s4 = *(const float4*)(sum_tile + bh * 16 + l4 * 4);
    float inv[4] = {1.f / s4.x, 1.f / s4.y, 1.f / s4.z, 1.f / s4.w};
#pragma unroll
    for (int df = 0; df < 4; ++df)
#pragma unroll
      for (int r = 0; r < 4; ++r) {
        const int i = l4 * 4 + r;
        float val = acc_o[bx][df][r] * inv[r];
        x_ws[((size_t)g * SB + i0 + i) * DM + bh * DKH + df * 16 + l15] = f2bf(val);
      }
  }
}

// ---------------- launch ----------------
extern "C" void kernel_launch(void* const* d_in, const int* in_sizes, int n_in,
                              void* d_out, int out_size, void* d_ws, size_t ws_size,
                              hipStream_t stream) {
  const float* query = (const float*)d_in[0];
  const float* key_  = (const float*)d_in[1];
  const float* value = (const float*)d_in[2];
  const int*   mask  = (const int*)d_in[3];
  const float* rel   = (const float*)d_in[4];
  const float* Wq = (const float*)d_in[5];
  const float* Wk = (const float*)d_in[6];
  const float* Wv = (const float*)d_in[7];
  const float* Wo = (const float*)d_in[8];
  const float* bq = (const float*)d_in[9];
  const float* bk = (const float*)d_in[10];
  const float* bv = (const float*)d_in[11];
  const float* bo = (const float*)d_in[12];
  float* out = (float*)d_out;
  char* ws = (char*)d_ws;

  u16* Xq   = (u16*)(ws + (0ull));
  u16* Xk   = (u16*)(ws + (8ull << 20));
  u16* Xv   = (u16*)(ws + (16ull << 20));
  u16* WqT  = (u16*)(ws + (24ull << 20));
  u16* WkT  = (u16*)(ws + (26ull << 20));
  u16* WvT  = (u16*)(ws + (28ull << 20));
  u16* WoT  = (u16*)(ws + (30ull << 20));
  u16* q_ws = (u16*)(ws + (32ull << 20));
  u16* k_ws = (u16*)(ws + (40ull << 20));
  u16* vT_ws= (u16*)(ws + (48ull << 20));
  u16* x_ws = (u16*)(ws + (56ull << 20));

  ra_convert_in<<<dim3(1024, 3), 256, 0, stream>>>(query, key_, value, Xq, Xk, Xv);
  ra_transpose_w<<<dim3(32, 32, 4), dim3(32, 8), 0, stream>>>(Wq, Wk, Wv, Wo, WqT, WkT, WvT, WoT);
  ra_proj_gemm<<<dim3(32, 8, 3), 256, 0, stream>>>(Xq, Xk, Xv, WqT, WkT, WvT, bq, bk, bv,
                                                   q_ws, k_ws, vT_ws);
  ra_attn<<<dim3(64, 4), 512, 0, stream>>>(q_ws, k_ws, vT_ws, mask, rel, x_ws);
  ra_out_gemm<<<dim3(32, 8), 256, 0, stream>>>(x_ws, WoT, bo, out);
}